// Round 5
// baseline (221.541 us; speedup 1.0000x reference)
//
#include <hip/hip_runtime.h>

typedef __attribute__((ext_vector_type(8))) short short8;
typedef __attribute__((ext_vector_type(4))) float f32x4;
typedef __attribute__((ext_vector_type(16))) float f32x16;

__device__ __forceinline__ float bf2f(unsigned short u) {
    union { unsigned int i; float f; } c; c.i = ((unsigned int)u) << 16; return c.f;
}
__device__ __forceinline__ unsigned short f2bf(float f) {   // RNE
    union { float f; unsigned int i; } c; c.f = f;
    unsigned int u = c.i;
    return (unsigned short)((u + 0x7fffu + ((u >> 16) & 1u)) >> 16);
}

// async global->LDS, 16B per lane. LDS dest = wave-uniform base + lane*16.
__device__ __forceinline__ void glds16(const void* g, void* l) {
    __builtin_amdgcn_global_load_lds(
        (const __attribute__((address_space(1))) unsigned int*)g,
        (__attribute__((address_space(3))) unsigned int*)l, 16, 0, 0);
}

union i4s8 { int4 i; short8 s; };

// ---------------------------------------------------------------------------
// prep: fp32->bf16 for x / qkv_w / proj_w, plus softmax bound MB2.
// ---------------------------------------------------------------------------
__global__ __launch_bounds__(256) void prep(
    const float* __restrict__ x, const float* __restrict__ qkv_w,
    const float* __restrict__ proj_w,
    const float* __restrict__ qn_w, const float* __restrict__ kn_w,
    unsigned short* __restrict__ xb, unsigned short* __restrict__ qwb,
    unsigned short* __restrict__ pwb, float* __restrict__ mb2)
{
    const int b = blockIdx.x, tid = threadIdx.x;
    const float* src; unsigned short* dst; int i;
    if (b < 4096)      { src = x;      dst = xb;  i = b * 256 + tid; }
    else if (b < 7168) { src = qkv_w;  dst = qwb; i = (b - 4096) * 256 + tid; }
    else if (b < 8192) { src = proj_w; dst = pwb; i = (b - 7168) * 256 + tid; }
    else {
        if (tid < 64) {
            float a = fabsf(qn_w[tid]), bb = fabsf(kn_w[tid]);
#pragma unroll
            for (int off = 32; off; off >>= 1) {
                a = fmaxf(a, __shfl_xor(a, off));
                bb = fmaxf(bb, __shfl_xor(bb, off));
            }
            if (tid == 0) *mb2 = 8.0f * a * bb * 1.4426950408889634f;
        }
        return;
    }
    float4 v = ((const float4*)src)[i];
    ushort4 o;
    o.x = f2bf(v.x); o.y = f2bf(v.y); o.z = f2bf(v.z); o.w = f2bf(v.w);
    ((ushort4*)dst)[i] = o;
}

// ---------------------------------------------------------------------------
// QKV GEMM (NT) + fused bias + RMSNorm + segmented RoPE epilogue.
// 128x128 tile, BK=32, 4 waves 2x2. V-blocks (t3==2, block-uniform) transpose
// the tile through LDS and store coalesced b128 runs into vt[bh][d][n].
// ---------------------------------------------------------------------------
__global__ __launch_bounds__(256) void gemm_qkv(
    const unsigned short* __restrict__ A,
    const unsigned short* __restrict__ W,
    const float* __restrict__ bias,
    const float* __restrict__ qn_w, const float* __restrict__ kn_w,
    unsigned short* __restrict__ qb, unsigned short* __restrict__ kb,
    unsigned short* __restrict__ vt)
{
    __shared__ unsigned short pool[128 * 136];   // As | Ws in-loop; T in v-epilogue
    const int tid = threadIdx.x;
    const int w = tid >> 6, l = tid & 63, quad = l >> 4, low = l & 15;
    const int m0 = blockIdx.y * 128, n0 = blockIdx.x * 128;
    const int wm = w >> 1, wn = w & 1;
    const int K = 1024;

    f32x4 acc[4][4];
#pragma unroll
    for (int i = 0; i < 4; i++)
#pragma unroll
        for (int j = 0; j < 4; j++) acc[i][j] = (f32x4){0.f, 0.f, 0.f, 0.f};

    const int r1 = tid >> 2, p1 = tid & 3;
    const int c1 = p1 ^ ((r1 >> 1) & 3);
    const int r2 = r1 + 64;
    const int c2 = p1 ^ ((r2 >> 1) & 3);
    const unsigned short* ga1 = A + (size_t)(m0 + r1) * K + c1 * 8;
    const unsigned short* ga2 = A + (size_t)(m0 + r2) * K + c2 * 8;
    const unsigned short* gw1 = W + (size_t)(n0 + r1) * K + c1 * 8;
    const unsigned short* gw2 = W + (size_t)(n0 + r2) * K + c2 * 8;
    char* lA = (char*)pool + (w << 10);
    char* lW = (char*)pool + 8192 + (w << 10);

    for (int k0 = 0; k0 < K; k0 += 32) {
        __syncthreads();
        glds16(ga1 + k0, lA);
        glds16(ga2 + k0, lA + 4096);
        glds16(gw1 + k0, lW);
        glds16(gw2 + k0, lW + 4096);
        __syncthreads();
        short8 af[4], wf[4];
#pragma unroll
        for (int i = 0; i < 4; i++) {
            const int ra = wm * 64 + i * 16 + low;
            af[i] = *(const short8*)&pool[ra * 32 + (quad ^ ((ra >> 1) & 3)) * 8];
            const int rw = wn * 64 + i * 16 + low;
            wf[i] = *(const short8*)&pool[4096 + rw * 32 + (quad ^ ((rw >> 1) & 3)) * 8];
        }
#pragma unroll
        for (int i = 0; i < 4; i++)
#pragma unroll
            for (int j = 0; j < 4; j++)
                acc[i][j] = __builtin_amdgcn_mfma_f32_16x16x32_bf16(
                    af[i], wf[j], acc[i][j], 0, 0, 0);
    }

    const int colbase = n0 + wn * 64;
    const int t3 = n0 >> 10;                   // block-uniform (128 | 1024)
    const int hh = (colbase & 1023) >> 6;

    if (t3 == 2) {
        // ---- V: transpose through LDS, coalesced stores to vt[bh][d][n] ----
        __syncthreads();                       // all As/Ws reads done
#pragma unroll
        for (int i = 0; i < 4; i++)
#pragma unroll
            for (int j = 0; j < 4; j++) {
                const int c = wn * 64 + j * 16 + low;
                const float bv = bias[n0 + c];
#pragma unroll
                for (int reg = 0; reg < 4; reg++) {
                    const int r = wm * 64 + i * 16 + quad * 4 + reg;
                    pool[c * 136 + r] = f2bf(acc[i][j][reg] + bv);
                }
            }
        __syncthreads();
        const int b_ = m0 >> 11, nbase = m0 & 2047;
        const int rch = (tid & 15) * 8;
#pragma unroll
        for (int p = 0; p < 8; p++) {
            const int c = (tid >> 4) + p * 16;
            const int gc = n0 + c;
            const int h2 = (gc & 1023) >> 6, d = gc & 63;
            const short8 vv = *(const short8*)&pool[c * 136 + rch];
            *(short8*)(vt + ((size_t)((b_ * 16 + h2) * 64 + d)) * 2048 + nbase + rch) = vv;
        }
        return;
    }

    // ---- Q/K: fused RMSNorm + segmented RoPE ----
    const float* nw = (t3 == 0) ? qn_w : kn_w;
    float wv4[4];
#pragma unroll
    for (int j = 0; j < 4; j++) wv4[j] = nw[j * 16 + low];
    const float c0 = -2.0f * 13.287712379549449f / 64.0f;
    const float invA = exp2f(c0 * (float)low);
    const float invB = exp2f(c0 * (float)(16 + low));
    unsigned short* dqk = (t3 == 0) ? qb : kb;

#pragma unroll
    for (int i = 0; i < 4; i++) {
#pragma unroll
        for (int reg = 0; reg < 4; reg++) {
            const int gm = m0 + wm * 64 + i * 16 + quad * 4 + reg;
            const int b_ = gm >> 11, npos = gm & 2047;
            float v[4];
#pragma unroll
            for (int j = 0; j < 4; j++)
                v[j] = acc[i][j][reg] + bias[colbase + j * 16 + low];
            float ss = v[0]*v[0] + v[1]*v[1] + v[2]*v[2] + v[3]*v[3];
            ss += __shfl_xor(ss, 1); ss += __shfl_xor(ss, 2);
            ss += __shfl_xor(ss, 4); ss += __shfl_xor(ss, 8);
            const float r = rsqrtf(ss * (1.0f / 64.0f) + 1e-6f);
            float nv[4];
#pragma unroll
            for (int j = 0; j < 4; j++) nv[j] = v[j] * r * wv4[j];
            float o0, o1, o2, o3;
            if (npos < 1536) {
                const float p = (float)((npos < 1024) ? npos : (npos - 1024));
                float sA, cA, sB, cB;
                __sincosf(p * invA, &sA, &cA);
                __sincosf(p * invB, &sB, &cB);
                o0 = nv[0] * cA - nv[2] * sA;
                o1 = nv[1] * cB - nv[3] * sB;
                o2 = nv[2] * cA + nv[0] * sA;
                o3 = nv[3] * cB + nv[1] * sB;
            } else { o0 = nv[0]; o1 = nv[1]; o2 = nv[2]; o3 = nv[3]; }
            unsigned short* drow =
                dqk + ((size_t)(b_ * 16 + hh) * 2048 + npos) * 64 + low;
            drow[0]  = f2bf(o0);
            drow[16] = f2bf(o1);
            drow[32] = f2bf(o2);
            drow[48] = f2bf(o3);
        }
    }
}

// ---------------------------------------------------------------------------
// MFMA flash attention, 32x32x16 shape, static-M softmax.
// Block = 128 q-rows of one bh; 4 waves x 32 q-rows; grid (16,32).
// S^T via mfma(K,Q) -> lane holds 16 keys for its q-row; exp'd P becomes the
// PV A-fragment after one half-wave exchange (shfl_xor 32) + cndmask.
// Row-sum via MFMA vs all-ones B. No P LDS round-trip.
// ---------------------------------------------------------------------------
__global__ __launch_bounds__(256) void flash_mfma(
    const unsigned short* __restrict__ qg, const unsigned short* __restrict__ kg,
    const unsigned short* __restrict__ vg, unsigned short* __restrict__ ao,
    const float* __restrict__ mb2p)
{
    __shared__ unsigned short Ks[64 * 64];
    __shared__ unsigned short Vs[64 * 64];

    const int tid = threadIdx.x;
    const int w = tid >> 6, lane = tid & 63, h5 = lane >> 5, l5 = lane & 31;
    const int bh = blockIdx.y, q0 = blockIdx.x * 128;
    const float MB2 = *mb2p;
    const float SCL = 0.125f * 1.4426950408889634f;

    // Q B-fragments: B[k=d=kstep*16+h5*8+j][n=qrow=l5]
    short8 qf[4];
    {
        const unsigned short* qrow = qg + ((size_t)bh * 2048 + q0 + w * 32 + l5) * 64;
#pragma unroll
        for (int ks = 0; ks < 4; ks++)
            qf[ks] = *(const short8*)(qrow + ks * 16 + h5 * 8);
    }

    f32x16 o0, o1, ls;
#pragma unroll
    for (int i = 0; i < 16; i++) { o0[i] = 0.f; o1[i] = 0.f; ls[i] = 0.f; }
    i4s8 ones; ones.i = make_int4(0x3F803F80, 0x3F803F80, 0x3F803F80, 0x3F803F80);

    const int kr1 = tid >> 3, kp1 = tid & 7, kc1 = kp1 ^ (kr1 & 7);
    const int kr2 = kr1 + 32, kc2 = kp1 ^ (kr2 & 7);
    const unsigned short* gk1 = kg + ((size_t)bh * 2048 + kr1) * 64 + kc1 * 8;
    const unsigned short* gk2 = kg + ((size_t)bh * 2048 + kr2) * 64 + kc2 * 8;
    const unsigned short* gv1 = vg + ((size_t)bh * 64 + kr1) * 2048 + kc1 * 8;
    const unsigned short* gv2 = vg + ((size_t)bh * 64 + kr2) * 2048 + kc2 * 8;
    char* lK = (char*)Ks + (w << 10);
    char* lV = (char*)Vs + (w << 10);

    for (int kt = 0; kt < 32; kt++) {
        const size_t ko = (size_t)kt * 4096;   // K: 64 rows x 64 d
        const int vo = kt * 64;                // V^T: 64-key window
        __syncthreads();
        glds16(gk1 + ko, lK);
        glds16(gk2 + ko, lK + 4096);
        glds16(gv1 + vo, lV);
        glds16(gv2 + vo, lV + 4096);
        __syncthreads();

#pragma unroll
        for (int kbk = 0; kbk < 2; kbk++) {
            // S^T = K·Q^T over d=64: A=K[m=key=kbk*32+l5][k=d], B=qf
            f32x16 s;
#pragma unroll
            for (int i = 0; i < 16; i++) s[i] = 0.f;
            const int krow = kbk * 32 + l5;
#pragma unroll
            for (int ks = 0; ks < 4; ks++) {
                const int ch = (h5 + 2 * ks) ^ (krow & 7);
                const short8 kf = *(const short8*)&Ks[krow * 64 + ch * 8];
                s = __builtin_amdgcn_mfma_f32_32x32x16_bf16(kf, qf[ks], s, 0, 0, 0);
            }
            // lane holds keys kbk*32 + (reg&3)+8*(reg>>2)+4*h5 for qrow=l5
            unsigned int dw[8], pdw[8];
#pragma unroll
            for (int r = 0; r < 8; r++) {
                union { float f; unsigned int u; } a, b;
                a.f = exp2f(fmaf(s[2 * r],     SCL, -MB2));
                b.f = exp2f(fmaf(s[2 * r + 1], SCL, -MB2));
                dw[r] = __builtin_amdgcn_perm(b.u, a.u, 0x07060302u);  // [bf16(a)|bf16(b)<<16]
            }
#pragma unroll
            for (int r = 0; r < 8; r++) pdw[r] = __shfl_xor((int)dw[r], 32);
            // assemble PV A-frags: A[m=qrow=l5][k=key=kstep*16+h5*8+j]
            i4s8 f0, f1;
            f0.i.x = h5 ? pdw[2] : dw[0];
            f0.i.y = h5 ? pdw[3] : dw[1];
            f0.i.z = h5 ? dw[2]  : pdw[0];
            f0.i.w = h5 ? dw[3]  : pdw[1];
            f1.i.x = h5 ? pdw[6] : dw[4];
            f1.i.y = h5 ? pdw[7] : dw[5];
            f1.i.z = h5 ? dw[6]  : pdw[4];
            f1.i.w = h5 ? dw[7]  : pdw[5];

            ls = __builtin_amdgcn_mfma_f32_32x32x16_bf16(f0.s, ones.s, ls, 0, 0, 0);
            ls = __builtin_amdgcn_mfma_f32_32x32x16_bf16(f1.s, ones.s, ls, 0, 0, 0);

            // PV: B = V[k=key][n=d] from Vs[d][key]
#pragma unroll
            for (int nb = 0; nb < 2; nb++) {
                const int vrow = nb * 32 + l5;
                const int chb = kbk * 4 + h5;
                const short8 vfa = *(const short8*)&Vs[vrow * 64 + ((chb    ) ^ (vrow & 7)) * 8];
                const short8 vfb = *(const short8*)&Vs[vrow * 64 + ((chb + 2) ^ (vrow & 7)) * 8];
                f32x16& oo = nb ? o1 : o0;
                oo = __builtin_amdgcn_mfma_f32_32x32x16_bf16(f0.s, vfa, oo, 0, 0, 0);
                oo = __builtin_amdgcn_mfma_f32_32x32x16_bf16(f1.s, vfb, oo, 0, 0, 0);
            }
        }
    }

    // epilogue: lane holds (qrow=(reg&3)+8*(reg>>2)+4*h5 + w*32 + q0, d=nb*32+l5)
    const int b_ = bh >> 4, h = bh & 15;
    float inv[16];
#pragma unroll
    for (int r = 0; r < 16; r++) inv[r] = 1.0f / ls[r];
#pragma unroll
    for (int r = 0; r < 16; r++) {
        const int n = q0 + w * 32 + (r & 3) + 8 * (r >> 2) + 4 * h5;
        const size_t rowb = ((size_t)(b_ * 2048 + n)) * 1024 + h * 64;
        ao[rowb + l5]      = f2bf(o0[r] * inv[r]);
        ao[rowb + 32 + l5] = f2bf(o1[r] * inv[r]);
    }
}

// ---------------------------------------------------------------------------
// Output projection: 64x128 tile, BK=32 -> grid (8,64), fp32 out.
// ---------------------------------------------------------------------------
__global__ __launch_bounds__(256) void gemm_out(
    const unsigned short* __restrict__ A,
    const unsigned short* __restrict__ W,
    const float* __restrict__ bias,
    float* __restrict__ outp)
{
    __shared__ unsigned short As[64 * 32];
    __shared__ unsigned short Ws[128 * 32];
    const int tid = threadIdx.x;
    const int w = tid >> 6, l = tid & 63, quad = l >> 4, low = l & 15;
    const int m0 = blockIdx.y * 64, n0 = blockIdx.x * 128;
    const int wm = w >> 1, wn = w & 1;
    const int K = 1024;

    f32x4 acc[2][4];
#pragma unroll
    for (int i = 0; i < 2; i++)
#pragma unroll
        for (int j = 0; j < 4; j++) acc[i][j] = (f32x4){0.f, 0.f, 0.f, 0.f};

    const int r1 = tid >> 2, p1 = tid & 3;
    const int c1 = p1 ^ ((r1 >> 1) & 3);
    const int r2 = r1 + 64;
    const int c2 = p1 ^ ((r2 >> 1) & 3);
    const unsigned short* ga = A + (size_t)(m0 + r1) * K + c1 * 8;
    const unsigned short* gw1 = W + (size_t)(n0 + r1) * K + c1 * 8;
    const unsigned short* gw2 = W + (size_t)(n0 + r2) * K + c2 * 8;
    char* lA = (char*)As + (w << 10);
    char* lW = (char*)Ws + (w << 10);

    for (int k0 = 0; k0 < K; k0 += 32) {
        __syncthreads();
        glds16(ga + k0, lA);
        glds16(gw1 + k0, lW);
        glds16(gw2 + k0, lW + 4096);
        __syncthreads();
        short8 af[2], wf[4];
#pragma unroll
        for (int i = 0; i < 2; i++) {
            const int ra = wm * 32 + i * 16 + low;
            af[i] = *(const short8*)&As[ra * 32 + (quad ^ ((ra >> 1) & 3)) * 8];
        }
#pragma unroll
        for (int j = 0; j < 4; j++) {
            const int rw = wn * 64 + j * 16 + low;
            wf[j] = *(const short8*)&Ws[rw * 32 + (quad ^ ((rw >> 1) & 3)) * 8];
        }
#pragma unroll
        for (int i = 0; i < 2; i++)
#pragma unroll
            for (int j = 0; j < 4; j++)
                acc[i][j] = __builtin_amdgcn_mfma_f32_16x16x32_bf16(
                    af[i], wf[j], acc[i][j], 0, 0, 0);
    }

#pragma unroll
    for (int i = 0; i < 2; i++)
#pragma unroll
        for (int j = 0; j < 4; j++) {
            const int gc = n0 + wn * 64 + j * 16 + low;
            const float bv = bias[gc];
#pragma unroll
            for (int reg = 0; reg < 4; reg++) {
                const int gm = m0 + wm * 32 + i * 16 + quad * 4 + reg;
                outp[(size_t)gm * 1024 + gc] = acc[i][j][reg] + bv;
            }
        }
}

// ---------------------------------------------------------------------------
extern "C" void kernel_launch(void* const* d_in, const int* in_sizes, int n_in,
                              void* d_out, int out_size, void* d_ws, size_t ws_size,
                              hipStream_t stream)
{
    const float* x      = (const float*)d_in[0];
    const float* qkv_w  = (const float*)d_in[1];
    const float* qkv_b  = (const float*)d_in[2];
    const float* qn_w   = (const float*)d_in[3];
    const float* kn_w   = (const float*)d_in[4];
    const float* proj_w = (const float*)d_in[5];
    const float* proj_b = (const float*)d_in[6];

    char* base = (char*)d_ws;
    float* mb2          = (float*)base;                                 // 256 B
    unsigned short* xb  = (unsigned short*)(base + 256);                // 8 MB
    unsigned short* qwb = xb  + 4194304;                                // 6 MB
    unsigned short* pwb = qwb + 3145728;                                // 2 MB
    unsigned short* qb  = pwb + 1048576;                                // 8 MB
    unsigned short* kb  = qb  + 4194304;                                // 8 MB
    unsigned short* vt  = kb  + 4194304;                                // 8 MB
    unsigned short* ao  = vt  + 4194304;                                // 8 MB

    prep<<<8193, 256, 0, stream>>>(x, qkv_w, proj_w, qn_w, kn_w, xb, qwb, pwb, mb2);

    gemm_qkv<<<dim3(24, 32), 256, 0, stream>>>(xb, qwb, qkv_b, qn_w, kn_w,
                                               qb, kb, vt);

    flash_mfma<<<dim3(16, 32), 256, 0, stream>>>(qb, kb, vt, ao, mb2);

    gemm_out<<<dim3(8, 64), 256, 0, stream>>>(ao, pwb, proj_b, (float*)d_out);
}

// Round 6
// 216.727 us; speedup vs baseline: 1.0222x; 1.0222x over previous
//
#include <hip/hip_runtime.h>

typedef __attribute__((ext_vector_type(8))) short short8;
typedef __attribute__((ext_vector_type(4))) float f32x4;
typedef __attribute__((ext_vector_type(16))) float f32x16;

__device__ __forceinline__ float bf2f(unsigned short u) {
    union { unsigned int i; float f; } c; c.i = ((unsigned int)u) << 16; return c.f;
}
__device__ __forceinline__ unsigned short f2bf(float f) {   // RNE
    union { float f; unsigned int i; } c; c.f = f;
    unsigned int u = c.i;
    return (unsigned short)((u + 0x7fffu + ((u >> 16) & 1u)) >> 16);
}

// async global->LDS, 16B per lane. LDS dest = wave-uniform base + lane*16.
__device__ __forceinline__ void glds16(const void* g, void* l) {
    __builtin_amdgcn_global_load_lds(
        (const __attribute__((address_space(1))) unsigned int*)g,
        (__attribute__((address_space(3))) unsigned int*)l, 16, 0, 0);
}

union i4s8 { int4 i; short8 s; };

// ---------------------------------------------------------------------------
// prep: fp32->bf16 for x / qkv_w / proj_w, plus softmax bound MB2.
// ---------------------------------------------------------------------------
__global__ __launch_bounds__(256) void prep(
    const float* __restrict__ x, const float* __restrict__ qkv_w,
    const float* __restrict__ proj_w,
    const float* __restrict__ qn_w, const float* __restrict__ kn_w,
    unsigned short* __restrict__ xb, unsigned short* __restrict__ qwb,
    unsigned short* __restrict__ pwb, float* __restrict__ mb2)
{
    const int b = blockIdx.x, tid = threadIdx.x;
    const float* src; unsigned short* dst; int i;
    if (b < 4096)      { src = x;      dst = xb;  i = b * 256 + tid; }
    else if (b < 7168) { src = qkv_w;  dst = qwb; i = (b - 4096) * 256 + tid; }
    else if (b < 8192) { src = proj_w; dst = pwb; i = (b - 7168) * 256 + tid; }
    else {
        if (tid < 64) {
            float a = fabsf(qn_w[tid]), bb = fabsf(kn_w[tid]);
#pragma unroll
            for (int off = 32; off; off >>= 1) {
                a = fmaxf(a, __shfl_xor(a, off));
                bb = fmaxf(bb, __shfl_xor(bb, off));
            }
            if (tid == 0) *mb2 = 8.0f * a * bb * 1.4426950408889634f;
        }
        return;
    }
    float4 v = ((const float4*)src)[i];
    ushort4 o;
    o.x = f2bf(v.x); o.y = f2bf(v.y); o.z = f2bf(v.z); o.w = f2bf(v.w);
    ((ushort4*)dst)[i] = o;
}

// ---------------------------------------------------------------------------
// QKV GEMM (NT) + fused bias + RMSNorm + segmented RoPE epilogue.
// 128x128 tile, BK=32, 4 waves 2x2. V-blocks transpose through LDS and store
// coalesced b128 runs into vt[bh][d][n]. (unchanged from round 5)
// ---------------------------------------------------------------------------
__global__ __launch_bounds__(256) void gemm_qkv(
    const unsigned short* __restrict__ A,
    const unsigned short* __restrict__ W,
    const float* __restrict__ bias,
    const float* __restrict__ qn_w, const float* __restrict__ kn_w,
    unsigned short* __restrict__ qb, unsigned short* __restrict__ kb,
    unsigned short* __restrict__ vt)
{
    __shared__ unsigned short pool[128 * 136];
    const int tid = threadIdx.x;
    const int w = tid >> 6, l = tid & 63, quad = l >> 4, low = l & 15;
    const int m0 = blockIdx.y * 128, n0 = blockIdx.x * 128;
    const int wm = w >> 1, wn = w & 1;
    const int K = 1024;

    f32x4 acc[4][4];
#pragma unroll
    for (int i = 0; i < 4; i++)
#pragma unroll
        for (int j = 0; j < 4; j++) acc[i][j] = (f32x4){0.f, 0.f, 0.f, 0.f};

    const int r1 = tid >> 2, p1 = tid & 3;
    const int c1 = p1 ^ ((r1 >> 1) & 3);
    const int r2 = r1 + 64;
    const int c2 = p1 ^ ((r2 >> 1) & 3);
    const unsigned short* ga1 = A + (size_t)(m0 + r1) * K + c1 * 8;
    const unsigned short* ga2 = A + (size_t)(m0 + r2) * K + c2 * 8;
    const unsigned short* gw1 = W + (size_t)(n0 + r1) * K + c1 * 8;
    const unsigned short* gw2 = W + (size_t)(n0 + r2) * K + c2 * 8;
    char* lA = (char*)pool + (w << 10);
    char* lW = (char*)pool + 8192 + (w << 10);

    for (int k0 = 0; k0 < K; k0 += 32) {
        __syncthreads();
        glds16(ga1 + k0, lA);
        glds16(ga2 + k0, lA + 4096);
        glds16(gw1 + k0, lW);
        glds16(gw2 + k0, lW + 4096);
        __syncthreads();
        short8 af[4], wf[4];
#pragma unroll
        for (int i = 0; i < 4; i++) {
            const int ra = wm * 64 + i * 16 + low;
            af[i] = *(const short8*)&pool[ra * 32 + (quad ^ ((ra >> 1) & 3)) * 8];
            const int rw = wn * 64 + i * 16 + low;
            wf[i] = *(const short8*)&pool[4096 + rw * 32 + (quad ^ ((rw >> 1) & 3)) * 8];
        }
#pragma unroll
        for (int i = 0; i < 4; i++)
#pragma unroll
            for (int j = 0; j < 4; j++)
                acc[i][j] = __builtin_amdgcn_mfma_f32_16x16x32_bf16(
                    af[i], wf[j], acc[i][j], 0, 0, 0);
    }

    const int colbase = n0 + wn * 64;
    const int t3 = n0 >> 10;
    const int hh = (colbase & 1023) >> 6;

    if (t3 == 2) {
        __syncthreads();
#pragma unroll
        for (int i = 0; i < 4; i++)
#pragma unroll
            for (int j = 0; j < 4; j++) {
                const int c = wn * 64 + j * 16 + low;
                const float bv = bias[n0 + c];
#pragma unroll
                for (int reg = 0; reg < 4; reg++) {
                    const int r = wm * 64 + i * 16 + quad * 4 + reg;
                    pool[c * 136 + r] = f2bf(acc[i][j][reg] + bv);
                }
            }
        __syncthreads();
        const int b_ = m0 >> 11, nbase = m0 & 2047;
        const int rch = (tid & 15) * 8;
#pragma unroll
        for (int p = 0; p < 8; p++) {
            const int c = (tid >> 4) + p * 16;
            const int gc = n0 + c;
            const int h2 = (gc & 1023) >> 6, d = gc & 63;
            const short8 vv = *(const short8*)&pool[c * 136 + rch];
            *(short8*)(vt + ((size_t)((b_ * 16 + h2) * 64 + d)) * 2048 + nbase + rch) = vv;
        }
        return;
    }

    const float* nw = (t3 == 0) ? qn_w : kn_w;
    float wv4[4];
#pragma unroll
    for (int j = 0; j < 4; j++) wv4[j] = nw[j * 16 + low];
    const float c0 = -2.0f * 13.287712379549449f / 64.0f;
    const float invA = exp2f(c0 * (float)low);
    const float invB = exp2f(c0 * (float)(16 + low));
    unsigned short* dqk = (t3 == 0) ? qb : kb;

#pragma unroll
    for (int i = 0; i < 4; i++) {
#pragma unroll
        for (int reg = 0; reg < 4; reg++) {
            const int gm = m0 + wm * 64 + i * 16 + quad * 4 + reg;
            const int b_ = gm >> 11, npos = gm & 2047;
            float v[4];
#pragma unroll
            for (int j = 0; j < 4; j++)
                v[j] = acc[i][j][reg] + bias[colbase + j * 16 + low];
            float ss = v[0]*v[0] + v[1]*v[1] + v[2]*v[2] + v[3]*v[3];
            ss += __shfl_xor(ss, 1); ss += __shfl_xor(ss, 2);
            ss += __shfl_xor(ss, 4); ss += __shfl_xor(ss, 8);
            const float r = rsqrtf(ss * (1.0f / 64.0f) + 1e-6f);
            float nv[4];
#pragma unroll
            for (int j = 0; j < 4; j++) nv[j] = v[j] * r * wv4[j];
            float o0, o1, o2, o3;
            if (npos < 1536) {
                const float p = (float)((npos < 1024) ? npos : (npos - 1024));
                float sA, cA, sB, cB;
                __sincosf(p * invA, &sA, &cA);
                __sincosf(p * invB, &sB, &cB);
                o0 = nv[0] * cA - nv[2] * sA;
                o1 = nv[1] * cB - nv[3] * sB;
                o2 = nv[2] * cA + nv[0] * sA;
                o3 = nv[3] * cB + nv[1] * sB;
            } else { o0 = nv[0]; o1 = nv[1]; o2 = nv[2]; o3 = nv[3]; }
            unsigned short* drow =
                dqk + ((size_t)(b_ * 16 + hh) * 2048 + npos) * 64 + low;
            drow[0]  = f2bf(o0);
            drow[16] = f2bf(o1);
            drow[32] = f2bf(o2);
            drow[48] = f2bf(o3);
        }
    }
}

// ---------------------------------------------------------------------------
// MFMA flash attention, 32x32x16, static-M softmax, KEY-SPLIT x2.
// Grid (16 qtiles, 32 bh, 2 halves); block = 128 q-rows, 4 waves x 32.
// Each block handles 1024 keys in 8 tiles of 128 (K 16KB + V^T 16KB LDS).
// O is a pure sum under static-M => halves combine in a later kernel.
// Partial O -> po bf16 [half][bh][q][d]; partial lsum -> pl fp32 [half][bh][q].
// ---------------------------------------------------------------------------
__global__ __launch_bounds__(256, 4) void flash_mfma(
    const unsigned short* __restrict__ qg, const unsigned short* __restrict__ kg,
    const unsigned short* __restrict__ vg, unsigned short* __restrict__ po,
    float* __restrict__ pl, const float* __restrict__ mb2p)
{
    __shared__ unsigned short Ks[128 * 64];   // [key][d]   rows 128B, 8 chunks
    __shared__ unsigned short Vs[64 * 128];   // [d][key]   rows 256B, 16 chunks

    const int tid = threadIdx.x;
    const int w = tid >> 6, lane = tid & 63, h5 = lane >> 5, l5 = lane & 31;
    const int bh = blockIdx.y, q0 = blockIdx.x * 128, half = blockIdx.z;
    const float MB2 = *mb2p;
    const float SCL = 0.125f * 1.4426950408889634f;

    // Q B-fragments: B[k=d=ks*16+h5*8+j][n=qrow=l5]
    short8 qf[4];
    {
        const unsigned short* qrow = qg + ((size_t)bh * 2048 + q0 + w * 32 + l5) * 64;
#pragma unroll
        for (int ks = 0; ks < 4; ks++)
            qf[ks] = *(const short8*)(qrow + ks * 16 + h5 * 8);
    }

    f32x16 o0, o1, ls;
#pragma unroll
    for (int i = 0; i < 16; i++) { o0[i] = 0.f; o1[i] = 0.f; ls[i] = 0.f; }
    i4s8 ones; ones.i = make_int4(0x3F803F80, 0x3F803F80, 0x3F803F80, 0x3F803F80);

    // staging: K row=tid>>3 (+32,+64,+96), pos=tid&7, col=pos^(row&7) (low3 inv.)
    //          V row=tid>>4 (+16,+32,+48), pos=tid&15, col=pos^(row&15) (low4 inv.)
    const int krr = tid >> 3, kc = (tid & 7) ^ (krr & 7);
    const unsigned short* gk = kg + ((size_t)bh * 2048 + krr) * 64 + kc * 8;
    const int vrr = tid >> 4, vc = (tid & 15) ^ (vrr & 15);
    const unsigned short* gv = vg + ((size_t)bh * 64 + vrr) * 2048 + vc * 8;
    char* lK = (char*)Ks + (w << 10);
    char* lV = (char*)Vs + (w << 10);
    const int kbase = half * 1024;

    for (int kt = 0; kt < 8; kt++) {
        const size_t ko = (size_t)(kbase + kt * 128);
        __syncthreads();
        glds16(gk + ko * 64,         lK);
        glds16(gk + ko * 64 + 2048,  lK + 4096);    // rows +32
        glds16(gk + ko * 64 + 4096,  lK + 8192);    // rows +64
        glds16(gk + ko * 64 + 6144,  lK + 12288);   // rows +96
        glds16(gv + ko,              lV);
        glds16(gv + ko + 32768,      lV + 4096);    // d-rows +16
        glds16(gv + ko + 65536,      lV + 8192);    // d-rows +32
        glds16(gv + ko + 98304,      lV + 12288);   // d-rows +48
        __syncthreads();

#pragma unroll
        for (int kbk = 0; kbk < 4; kbk++) {
            // S^T = K·Q^T: A = K[m=key=kbk*32+l5][k=d], B = qf
            f32x16 s;
#pragma unroll
            for (int i = 0; i < 16; i++) s[i] = 0.f;
            const int krow = kbk * 32 + l5;
#pragma unroll
            for (int ks = 0; ks < 4; ks++) {
                const int ch = (h5 + 2 * ks) ^ (krow & 7);
                const short8 kf = *(const short8*)&Ks[krow * 64 + ch * 8];
                s = __builtin_amdgcn_mfma_f32_32x32x16_bf16(kf, qf[ks], s, 0, 0, 0);
            }
            unsigned int dw[8], pdw[8];
#pragma unroll
            for (int r = 0; r < 8; r++) {
                union { float f; unsigned int u; } a, b;
                a.f = exp2f(fmaf(s[2 * r],     SCL, -MB2));
                b.f = exp2f(fmaf(s[2 * r + 1], SCL, -MB2));
                dw[r] = __builtin_amdgcn_perm(b.u, a.u, 0x07060302u);
            }
#pragma unroll
            for (int r = 0; r < 8; r++) pdw[r] = __shfl_xor((int)dw[r], 32);
            // PV A-frags: A[m=qrow=l5][k=key] (validated round 5)
            i4s8 f0, f1;
            f0.i.x = h5 ? pdw[2] : dw[0];
            f0.i.y = h5 ? pdw[3] : dw[1];
            f0.i.z = h5 ? dw[2]  : pdw[0];
            f0.i.w = h5 ? dw[3]  : pdw[1];
            f1.i.x = h5 ? pdw[6] : dw[4];
            f1.i.y = h5 ? pdw[7] : dw[5];
            f1.i.z = h5 ? dw[6]  : pdw[4];
            f1.i.w = h5 ? dw[7]  : pdw[5];

            ls = __builtin_amdgcn_mfma_f32_32x32x16_bf16(f0.s, ones.s, ls, 0, 0, 0);
            ls = __builtin_amdgcn_mfma_f32_32x32x16_bf16(f1.s, ones.s, ls, 0, 0, 0);

#pragma unroll
            for (int nb = 0; nb < 2; nb++) {
                const int vrow = nb * 32 + l5;
                const int chb = kbk * 4 + h5;
                const short8 vfa = *(const short8*)&Vs[vrow * 128 + ((chb    ) ^ (vrow & 15)) * 8];
                const short8 vfb = *(const short8*)&Vs[vrow * 128 + ((chb + 2) ^ (vrow & 15)) * 8];
                f32x16& oo = nb ? o1 : o0;
                oo = __builtin_amdgcn_mfma_f32_32x32x16_bf16(f0.s, vfa, oo, 0, 0, 0);
                oo = __builtin_amdgcn_mfma_f32_32x32x16_bf16(f1.s, vfb, oo, 0, 0, 0);
            }
        }
    }

    // epilogue: partial O (bf16) + partial lsum (fp32)
    unsigned short* pob = po + ((size_t)(half * 32 + bh)) * 2048 * 64;
    float* plb = pl + ((size_t)(half * 32 + bh)) * 2048;
#pragma unroll
    for (int r = 0; r < 16; r++) {
        const int qrow = q0 + w * 32 + (r & 3) + 8 * (r >> 2) + 4 * h5;
        pob[(size_t)qrow * 64 + l5]      = f2bf(o0[r]);
        pob[(size_t)qrow * 64 + 32 + l5] = f2bf(o1[r]);
        if (l5 == 0) plb[qrow] = ls[r];
    }
}

// ---------------------------------------------------------------------------
// combine: ao[b][n][h*64+d] = (po0+po1) / (pl0+pl1). 2048 blocks x 256 thr.
// ---------------------------------------------------------------------------
__global__ __launch_bounds__(256) void combine(
    const unsigned short* __restrict__ po, const float* __restrict__ pl,
    unsigned short* __restrict__ ao)
{
    const int g = blockIdx.x * 256 + threadIdx.x;   // 524288 = 32*2048*8
    const int row = g >> 3;                         // bh*2048 + n
    const int c8 = (g & 7) * 8;
    const int bh = row >> 11, n = row & 2047;
    const float inv = 1.0f / (pl[row] + pl[65536 + row]);
    const short8 a = *(const short8*)(po + (size_t)row * 64 + c8);
    const short8 b = *(const short8*)(po + 4194304 + (size_t)row * 64 + c8);
    short8 r;
#pragma unroll
    for (int j = 0; j < 8; j++)
        r[j] = (short)f2bf((bf2f((unsigned short)a[j]) + bf2f((unsigned short)b[j])) * inv);
    const int b_ = bh >> 4, h = bh & 15;
    *(short8*)(ao + ((size_t)(b_ * 2048 + n)) * 1024 + h * 64 + c8) = r;
}

// ---------------------------------------------------------------------------
// Output projection: 64x128 tile, BK=32 -> grid (8,64), fp32 out. (unchanged)
// ---------------------------------------------------------------------------
__global__ __launch_bounds__(256) void gemm_out(
    const unsigned short* __restrict__ A,
    const unsigned short* __restrict__ W,
    const float* __restrict__ bias,
    float* __restrict__ outp)
{
    __shared__ unsigned short As[64 * 32];
    __shared__ unsigned short Ws[128 * 32];
    const int tid = threadIdx.x;
    const int w = tid >> 6, l = tid & 63, quad = l >> 4, low = l & 15;
    const int m0 = blockIdx.y * 64, n0 = blockIdx.x * 128;
    const int wm = w >> 1, wn = w & 1;
    const int K = 1024;

    f32x4 acc[2][4];
#pragma unroll
    for (int i = 0; i < 2; i++)
#pragma unroll
        for (int j = 0; j < 4; j++) acc[i][j] = (f32x4){0.f, 0.f, 0.f, 0.f};

    const int r1 = tid >> 2, p1 = tid & 3;
    const int c1 = p1 ^ ((r1 >> 1) & 3);
    const int r2 = r1 + 64;
    const int c2 = p1 ^ ((r2 >> 1) & 3);
    const unsigned short* ga = A + (size_t)(m0 + r1) * K + c1 * 8;
    const unsigned short* gw1 = W + (size_t)(n0 + r1) * K + c1 * 8;
    const unsigned short* gw2 = W + (size_t)(n0 + r2) * K + c2 * 8;
    char* lA = (char*)As + (w << 10);
    char* lW = (char*)Ws + (w << 10);

    for (int k0 = 0; k0 < K; k0 += 32) {
        __syncthreads();
        glds16(ga + k0, lA);
        glds16(gw1 + k0, lW);
        glds16(gw2 + k0, lW + 4096);
        __syncthreads();
        short8 af[2], wf[4];
#pragma unroll
        for (int i = 0; i < 2; i++) {
            const int ra = wm * 32 + i * 16 + low;
            af[i] = *(const short8*)&As[ra * 32 + (quad ^ ((ra >> 1) & 3)) * 8];
        }
#pragma unroll
        for (int j = 0; j < 4; j++) {
            const int rw = wn * 64 + j * 16 + low;
            wf[j] = *(const short8*)&Ws[rw * 32 + (quad ^ ((rw >> 1) & 3)) * 8];
        }
#pragma unroll
        for (int i = 0; i < 2; i++)
#pragma unroll
            for (int j = 0; j < 4; j++)
                acc[i][j] = __builtin_amdgcn_mfma_f32_16x16x32_bf16(
                    af[i], wf[j], acc[i][j], 0, 0, 0);
    }

#pragma unroll
    for (int i = 0; i < 2; i++)
#pragma unroll
        for (int j = 0; j < 4; j++) {
            const int gc = n0 + wn * 64 + j * 16 + low;
            const float bv = bias[gc];
#pragma unroll
            for (int reg = 0; reg < 4; reg++) {
                const int gm = m0 + wm * 32 + i * 16 + quad * 4 + reg;
                outp[(size_t)gm * 1024 + gc] = acc[i][j][reg] + bv;
            }
        }
}

// ---------------------------------------------------------------------------
extern "C" void kernel_launch(void* const* d_in, const int* in_sizes, int n_in,
                              void* d_out, int out_size, void* d_ws, size_t ws_size,
                              hipStream_t stream)
{
    const float* x      = (const float*)d_in[0];
    const float* qkv_w  = (const float*)d_in[1];
    const float* qkv_b  = (const float*)d_in[2];
    const float* qn_w   = (const float*)d_in[3];
    const float* kn_w   = (const float*)d_in[4];
    const float* proj_w = (const float*)d_in[5];
    const float* proj_b = (const float*)d_in[6];

    // ws layout (~52.9 MB; dead xb/qwb region reused for po/pl):
    char* base = (char*)d_ws;
    float* mb2          = (float*)base;                 // 256 B
    unsigned short* pwb = (unsigned short*)(base + 256);// 2 MB
    unsigned short* qb  = pwb + 1048576;                // 8 MB
    unsigned short* kb  = qb  + 4194304;                // 8 MB
    unsigned short* vt  = kb  + 4194304;                // 8 MB
    unsigned short* ao  = vt  + 4194304;                // 8 MB
    unsigned short* xb  = ao  + 4194304;                // 8 MB  (dead after gemm_qkv)
    unsigned short* qwb = xb  + 4194304;                // 6 MB  (dead after gemm_qkv)
    unsigned short* po  = xb;                           // 16 MB (overlays xb+qwb+2MB)
    float* pl           = (float*)(po + 8388608);       // 512 KB

    prep<<<8193, 256, 0, stream>>>(x, qkv_w, proj_w, qn_w, kn_w, xb, qwb, pwb, mb2);

    gemm_qkv<<<dim3(24, 32), 256, 0, stream>>>(xb, qwb, qkv_b, qn_w, kn_w,
                                               qb, kb, vt);

    flash_mfma<<<dim3(16, 32, 2), 256, 0, stream>>>(qb, kb, vt, po, pl, mb2);

    combine<<<2048, 256, 0, stream>>>(po, pl, ao);

    gemm_out<<<dim3(8, 64), 256, 0, stream>>>(ao, pwb, proj_b, (float*)d_out);
}

// Round 7
// 213.214 us; speedup vs baseline: 1.0391x; 1.0165x over previous
//
#include <hip/hip_runtime.h>

typedef __attribute__((ext_vector_type(8))) short short8;
typedef __attribute__((ext_vector_type(4))) float f32x4;
typedef __attribute__((ext_vector_type(16))) float f32x16;

__device__ __forceinline__ float bf2f(unsigned short u) {
    union { unsigned int i; float f; } c; c.i = ((unsigned int)u) << 16; return c.f;
}
__device__ __forceinline__ unsigned short f2bf(float f) {   // RNE
    union { float f; unsigned int i; } c; c.f = f;
    unsigned int u = c.i;
    return (unsigned short)((u + 0x7fffu + ((u >> 16) & 1u)) >> 16);
}

// async global->LDS, 16B per lane. LDS dest = wave-uniform base + lane*16.
__device__ __forceinline__ void glds16(const void* g, void* l) {
    __builtin_amdgcn_global_load_lds(
        (const __attribute__((address_space(1))) unsigned int*)g,
        (__attribute__((address_space(3))) unsigned int*)l, 16, 0, 0);
}

union i4s8 { int4 i; short8 s; };

// SCL = (1/sqrt(64)) * log2(e), folded into q at gemm_qkv epilogue.
#define SCL_F 0.18033688011112042f

// ---------------------------------------------------------------------------
// prep: fp32->bf16 for x / qkv_w / proj_w.
// ---------------------------------------------------------------------------
__global__ __launch_bounds__(256) void prep(
    const float* __restrict__ x, const float* __restrict__ qkv_w,
    const float* __restrict__ proj_w,
    unsigned short* __restrict__ xb, unsigned short* __restrict__ qwb,
    unsigned short* __restrict__ pwb)
{
    const int b = blockIdx.x, tid = threadIdx.x;
    const float* src; unsigned short* dst; int i;
    if (b < 4096)      { src = x;      dst = xb;  i = b * 256 + tid; }
    else if (b < 7168) { src = qkv_w;  dst = qwb; i = (b - 4096) * 256 + tid; }
    else               { src = proj_w; dst = pwb; i = (b - 7168) * 256 + tid; }
    float4 v = ((const float4*)src)[i];
    ushort4 o;
    o.x = f2bf(v.x); o.y = f2bf(v.y); o.z = f2bf(v.z); o.w = f2bf(v.w);
    ((ushort4*)dst)[i] = o;
}

// ---------------------------------------------------------------------------
// QKV GEMM (NT) + fused bias + RMSNorm + segmented RoPE epilogue.
// 128x128 tile, BK=64 (16 iters, halved barrier count), 4 waves 2x2.
// q additionally scaled by SCL_F. V-tile transposed through LDS -> vt[bh][d][n].
// ---------------------------------------------------------------------------
__global__ __launch_bounds__(256) void gemm_qkv(
    const unsigned short* __restrict__ A,
    const unsigned short* __restrict__ W,
    const float* __restrict__ bias,
    const float* __restrict__ qn_w, const float* __restrict__ kn_w,
    unsigned short* __restrict__ qb, unsigned short* __restrict__ kb,
    unsigned short* __restrict__ vt)
{
    __shared__ unsigned short pool[128 * 136];   // loop: As 16KB | Ws 16KB; epi: 34.8KB
    const int tid = threadIdx.x;
    const int w = tid >> 6, l = tid & 63, quad = l >> 4, low = l & 15;
    const int m0 = blockIdx.y * 128, n0 = blockIdx.x * 128;
    const int wm = w >> 1, wn = w & 1;
    const int K = 1024;

    f32x4 acc[4][4];
#pragma unroll
    for (int i = 0; i < 4; i++)
#pragma unroll
        for (int j = 0; j < 4; j++) acc[i][j] = (f32x4){0.f, 0.f, 0.f, 0.f};

    // staging: 128 rows x 64 cols per matrix; thread row r=tid>>3 (+32/g), chunk=tid&7
    const int r1 = tid >> 3, p1 = tid & 7, c1 = p1 ^ (r1 & 7);
    const unsigned short* ga = A + (size_t)(m0 + r1) * K + c1 * 8;
    const unsigned short* gw = W + (size_t)(n0 + r1) * K + c1 * 8;
    char* lA = (char*)pool + (w << 10);
    char* lW = (char*)pool + 16384 + (w << 10);

    for (int k0 = 0; k0 < K; k0 += 64) {
        __syncthreads();
        glds16(ga + k0,            lA);
        glds16(ga + k0 + 32 * K,   lA + 4096);
        glds16(ga + k0 + 64 * K,   lA + 8192);
        glds16(ga + k0 + 96 * K,   lA + 12288);
        glds16(gw + k0,            lW);
        glds16(gw + k0 + 32 * K,   lW + 4096);
        glds16(gw + k0 + 64 * K,   lW + 8192);
        glds16(gw + k0 + 96 * K,   lW + 12288);
        __syncthreads();
#pragma unroll
        for (int ks = 0; ks < 2; ks++) {
            short8 af[4], wf[4];
#pragma unroll
            for (int i = 0; i < 4; i++) {
                const int ra = wm * 64 + i * 16 + low;
                af[i] = *(const short8*)&pool[ra * 64 + ((ks * 4 + quad) ^ (ra & 7)) * 8];
                const int rw = wn * 64 + i * 16 + low;
                wf[i] = *(const short8*)&pool[8192 + rw * 64 + ((ks * 4 + quad) ^ (rw & 7)) * 8];
            }
#pragma unroll
            for (int i = 0; i < 4; i++)
#pragma unroll
                for (int j = 0; j < 4; j++)
                    acc[i][j] = __builtin_amdgcn_mfma_f32_16x16x32_bf16(
                        af[i], wf[j], acc[i][j], 0, 0, 0);
        }
    }

    const int colbase = n0 + wn * 64;
    const int t3 = n0 >> 10;
    const int hh = (colbase & 1023) >> 6;

    if (t3 == 2) {
        __syncthreads();
#pragma unroll
        for (int i = 0; i < 4; i++)
#pragma unroll
            for (int j = 0; j < 4; j++) {
                const int c = wn * 64 + j * 16 + low;
                const float bv = bias[n0 + c];
#pragma unroll
                for (int reg = 0; reg < 4; reg++) {
                    const int r = wm * 64 + i * 16 + quad * 4 + reg;
                    pool[c * 136 + r] = f2bf(acc[i][j][reg] + bv);
                }
            }
        __syncthreads();
        const int b_ = m0 >> 11, nbase = m0 & 2047;
        const int rch = (tid & 15) * 8;
#pragma unroll
        for (int p = 0; p < 8; p++) {
            const int c = (tid >> 4) + p * 16;
            const int gc = n0 + c;
            const int h2 = (gc & 1023) >> 6, d = gc & 63;
            const short8 vv = *(const short8*)&pool[c * 136 + rch];
            *(short8*)(vt + ((size_t)((b_ * 16 + h2) * 64 + d)) * 2048 + nbase + rch) = vv;
        }
        return;
    }

    const float* nw = (t3 == 0) ? qn_w : kn_w;
    const float wscl = (t3 == 0) ? SCL_F : 1.0f;   // fold softmax scale into q
    float wv4[4];
#pragma unroll
    for (int j = 0; j < 4; j++) wv4[j] = nw[j * 16 + low] * wscl;
    const float c0 = -2.0f * 13.287712379549449f / 64.0f;
    const float invA = exp2f(c0 * (float)low);
    const float invB = exp2f(c0 * (float)(16 + low));
    unsigned short* dqk = (t3 == 0) ? qb : kb;

#pragma unroll
    for (int i = 0; i < 4; i++) {
#pragma unroll
        for (int reg = 0; reg < 4; reg++) {
            const int gm = m0 + wm * 64 + i * 16 + quad * 4 + reg;
            const int b_ = gm >> 11, npos = gm & 2047;
            float v[4];
#pragma unroll
            for (int j = 0; j < 4; j++)
                v[j] = acc[i][j][reg] + bias[colbase + j * 16 + low];
            float ss = v[0]*v[0] + v[1]*v[1] + v[2]*v[2] + v[3]*v[3];
            ss += __shfl_xor(ss, 1); ss += __shfl_xor(ss, 2);
            ss += __shfl_xor(ss, 4); ss += __shfl_xor(ss, 8);
            const float r = rsqrtf(ss * (1.0f / 64.0f) + 1e-6f);
            float nv[4];
#pragma unroll
            for (int j = 0; j < 4; j++) nv[j] = v[j] * r * wv4[j];
            float o0, o1, o2, o3;
            if (npos < 1536) {
                const float p = (float)((npos < 1024) ? npos : (npos - 1024));
                float sA, cA, sB, cB;
                __sincosf(p * invA, &sA, &cA);
                __sincosf(p * invB, &sB, &cB);
                o0 = nv[0] * cA - nv[2] * sA;
                o1 = nv[1] * cB - nv[3] * sB;
                o2 = nv[2] * cA + nv[0] * sA;
                o3 = nv[3] * cB + nv[1] * sB;
            } else { o0 = nv[0]; o1 = nv[1]; o2 = nv[2]; o3 = nv[3]; }
            unsigned short* drow =
                dqk + ((size_t)(b_ * 16 + hh) * 2048 + npos) * 64 + low;
            drow[0]  = f2bf(o0);
            drow[16] = f2bf(o1);
            drow[32] = f2bf(o2);
            drow[48] = f2bf(o3);
        }
    }
}

// ---------------------------------------------------------------------------
// MFMA flash attention, 32x32x16, static softmax (scale pre-folded into q).
// Block = 2 waves x 32 q-rows = 64 q-rows; grid (32,32,2) = 2048 blocks
// (8 blocks/CU, 16 waves/CU). 64-key LDS tiles (16 KB), 16 kt iters.
// O and lsum are pure sums -> halves combine later.
// ---------------------------------------------------------------------------
__global__ __launch_bounds__(128, 4) void flash_mfma(
    const unsigned short* __restrict__ qg, const unsigned short* __restrict__ kg,
    const unsigned short* __restrict__ vg, unsigned short* __restrict__ po,
    float* __restrict__ pl)
{
    __shared__ unsigned short Ks[64 * 64];   // [key][d]  rows 128B, 8 chunks
    __shared__ unsigned short Vs[64 * 64];   // [d][key window] rows 128B, 8 chunks

    const int tid = threadIdx.x;
    const int w = tid >> 6, lane = tid & 63, h5 = lane >> 5, l5 = lane & 31;
    const int bh = blockIdx.y, q0 = blockIdx.x * 64, half = blockIdx.z;

    // Q B-fragments: B[k=d=ks*16+h5*8+j][n=qrow=l5]
    short8 qf[4];
    {
        const unsigned short* qrow = qg + ((size_t)bh * 2048 + q0 + w * 32 + l5) * 64;
#pragma unroll
        for (int ks = 0; ks < 4; ks++)
            qf[ks] = *(const short8*)(qrow + ks * 16 + h5 * 8);
    }

    f32x16 o0, o1, ls;
#pragma unroll
    for (int i = 0; i < 16; i++) { o0[i] = 0.f; o1[i] = 0.f; ls[i] = 0.f; }
    i4s8 ones; ones.i = make_int4(0x3F803F80, 0x3F803F80, 0x3F803F80, 0x3F803F80);

    // staging: row = tid>>3 (0..15, +16/g), chunk = tid&7, col = chunk^(row&7)
    const int rr = tid >> 3, cc = (tid & 7) ^ (rr & 7);
    const unsigned short* gk = kg + ((size_t)bh * 2048 + rr) * 64 + cc * 8;
    const unsigned short* gv = vg + ((size_t)bh * 64 + rr) * 2048 + cc * 8;
    char* lK = (char*)Ks + (w << 10);
    char* lV = (char*)Vs + (w << 10);
    const int kbase = half * 1024;

    for (int kt = 0; kt < 16; kt++) {
        const size_t ko = (size_t)(kbase + kt * 64);
        __syncthreads();
        glds16(gk + ko * 64,          lK);
        glds16(gk + ko * 64 + 1024,   lK + 2048);    // key rows +16
        glds16(gk + ko * 64 + 2048,   lK + 4096);    // +32
        glds16(gk + ko * 64 + 3072,   lK + 6144);    // +48
        glds16(gv + ko,               lV);
        glds16(gv + ko + 32768,       lV + 2048);    // d rows +16
        glds16(gv + ko + 65536,       lV + 4096);    // +32
        glds16(gv + ko + 98304,       lV + 6144);    // +48
        __syncthreads();

#pragma unroll
        for (int kbk = 0; kbk < 2; kbk++) {
            // S^T = K·Q^T: A = K[m=key=kbk*32+l5][k=d], B = qf
            f32x16 s;
#pragma unroll
            for (int i = 0; i < 16; i++) s[i] = 0.f;
            const int krow = kbk * 32 + l5;
#pragma unroll
            for (int ks = 0; ks < 4; ks++) {
                const int ch = (h5 + 2 * ks) ^ (krow & 7);
                const short8 kf = *(const short8*)&Ks[krow * 64 + ch * 8];
                s = __builtin_amdgcn_mfma_f32_32x32x16_bf16(kf, qf[ks], s, 0, 0, 0);
            }
            unsigned int dw[8], pdw[8];
#pragma unroll
            for (int r = 0; r < 8; r++) {
                union { float f; unsigned int u; } a, b;
                a.f = exp2f(s[2 * r]);        // scale pre-folded into q
                b.f = exp2f(s[2 * r + 1]);
                dw[r] = __builtin_amdgcn_perm(b.u, a.u, 0x07060302u);
            }
#pragma unroll
            for (int r = 0; r < 8; r++) pdw[r] = __shfl_xor((int)dw[r], 32);
            // PV A-frags: A[m=qrow=l5][k=key] (validated rounds 5-6)
            i4s8 f0, f1;
            f0.i.x = h5 ? pdw[2] : dw[0];
            f0.i.y = h5 ? pdw[3] : dw[1];
            f0.i.z = h5 ? dw[2]  : pdw[0];
            f0.i.w = h5 ? dw[3]  : pdw[1];
            f1.i.x = h5 ? pdw[6] : dw[4];
            f1.i.y = h5 ? pdw[7] : dw[5];
            f1.i.z = h5 ? dw[6]  : pdw[4];
            f1.i.w = h5 ? dw[7]  : pdw[5];

            ls = __builtin_amdgcn_mfma_f32_32x32x16_bf16(f0.s, ones.s, ls, 0, 0, 0);
            ls = __builtin_amdgcn_mfma_f32_32x32x16_bf16(f1.s, ones.s, ls, 0, 0, 0);

#pragma unroll
            for (int nb = 0; nb < 2; nb++) {
                const int vrow = nb * 32 + l5;
                const int chb = kbk * 4 + h5;
                const short8 vfa = *(const short8*)&Vs[vrow * 64 + ((chb    ) ^ (vrow & 7)) * 8];
                const short8 vfb = *(const short8*)&Vs[vrow * 64 + ((chb + 2) ^ (vrow & 7)) * 8];
                f32x16& oo = nb ? o1 : o0;
                oo = __builtin_amdgcn_mfma_f32_32x32x16_bf16(f0.s, vfa, oo, 0, 0, 0);
                oo = __builtin_amdgcn_mfma_f32_32x32x16_bf16(f1.s, vfb, oo, 0, 0, 0);
            }
        }
    }

    // epilogue: partial O (bf16) + partial lsum (fp32)
    unsigned short* pob = po + ((size_t)(half * 32 + bh)) * 2048 * 64;
    float* plb = pl + ((size_t)(half * 32 + bh)) * 2048;
#pragma unroll
    for (int r = 0; r < 16; r++) {
        const int qrow = q0 + w * 32 + (r & 3) + 8 * (r >> 2) + 4 * h5;
        pob[(size_t)qrow * 64 + l5]      = f2bf(o0[r]);
        pob[(size_t)qrow * 64 + 32 + l5] = f2bf(o1[r]);
        if (l5 == 0) plb[qrow] = ls[r];
    }
}

// ---------------------------------------------------------------------------
// combine: ao[b][n][h*64+d] = (po0+po1) / (pl0+pl1). 2048 blocks x 256 thr.
// ---------------------------------------------------------------------------
__global__ __launch_bounds__(256) void combine(
    const unsigned short* __restrict__ po, const float* __restrict__ pl,
    unsigned short* __restrict__ ao)
{
    const int g = blockIdx.x * 256 + threadIdx.x;
    const int row = g >> 3;
    const int c8 = (g & 7) * 8;
    const int bh = row >> 11, n = row & 2047;
    const float inv = 1.0f / (pl[row] + pl[65536 + row]);
    const short8 a = *(const short8*)(po + (size_t)row * 64 + c8);
    const short8 b = *(const short8*)(po + 4194304 + (size_t)row * 64 + c8);
    short8 r;
#pragma unroll
    for (int j = 0; j < 8; j++)
        r[j] = (short)f2bf((bf2f((unsigned short)a[j]) + bf2f((unsigned short)b[j])) * inv);
    const int b_ = bh >> 4, h = bh & 15;
    *(short8*)(ao + ((size_t)(b_ * 2048 + n)) * 1024 + h * 64 + c8) = r;
}

// ---------------------------------------------------------------------------
// Output projection: 64x128 tile, BK=64 (16 iters), grid (8,64), fp32 out.
// ---------------------------------------------------------------------------
__global__ __launch_bounds__(256) void gemm_out(
    const unsigned short* __restrict__ A,
    const unsigned short* __restrict__ W,
    const float* __restrict__ bias,
    float* __restrict__ outp)
{
    __shared__ unsigned short As[64 * 64];    // 8 KB
    __shared__ unsigned short Ws[128 * 64];   // 16 KB
    const int tid = threadIdx.x;
    const int w = tid >> 6, l = tid & 63, quad = l >> 4, low = l & 15;
    const int m0 = blockIdx.y * 64, n0 = blockIdx.x * 128;
    const int wm = w >> 1, wn = w & 1;
    const int K = 1024;

    f32x4 acc[2][4];
#pragma unroll
    for (int i = 0; i < 2; i++)
#pragma unroll
        for (int j = 0; j < 4; j++) acc[i][j] = (f32x4){0.f, 0.f, 0.f, 0.f};

    const int r1 = tid >> 3, p1 = tid & 7, c1 = p1 ^ (r1 & 7);
    const unsigned short* ga = A + (size_t)(m0 + r1) * K + c1 * 8;
    const unsigned short* gw = W + (size_t)(n0 + r1) * K + c1 * 8;
    char* lA = (char*)As + (w << 10);
    char* lW = (char*)Ws + (w << 10);

    for (int k0 = 0; k0 < K; k0 += 64) {
        __syncthreads();
        glds16(ga + k0,           lA);
        glds16(ga + k0 + 32 * K,  lA + 4096);
        glds16(gw + k0,           lW);
        glds16(gw + k0 + 32 * K,  lW + 4096);
        glds16(gw + k0 + 64 * K,  lW + 8192);
        glds16(gw + k0 + 96 * K,  lW + 12288);
        __syncthreads();
#pragma unroll
        for (int ks = 0; ks < 2; ks++) {
            short8 af[2], wf[4];
#pragma unroll
            for (int i = 0; i < 2; i++) {
                const int ra = wm * 32 + i * 16 + low;
                af[i] = *(const short8*)&As[ra * 64 + ((ks * 4 + quad) ^ (ra & 7)) * 8];
            }
#pragma unroll
            for (int j = 0; j < 4; j++) {
                const int rw = wn * 64 + j * 16 + low;
                wf[j] = *(const short8*)&Ws[rw * 64 + ((ks * 4 + quad) ^ (rw & 7)) * 8];
            }
#pragma unroll
            for (int i = 0; i < 2; i++)
#pragma unroll
                for (int j = 0; j < 4; j++)
                    acc[i][j] = __builtin_amdgcn_mfma_f32_16x16x32_bf16(
                        af[i], wf[j], acc[i][j], 0, 0, 0);
        }
    }

#pragma unroll
    for (int i = 0; i < 2; i++)
#pragma unroll
        for (int j = 0; j < 4; j++) {
            const int gc = n0 + wn * 64 + j * 16 + low;
            const float bv = bias[gc];
#pragma unroll
            for (int reg = 0; reg < 4; reg++) {
                const int gm = m0 + wm * 32 + i * 16 + quad * 4 + reg;
                outp[(size_t)gm * 1024 + gc] = acc[i][j][reg] + bv;
            }
        }
}

// ---------------------------------------------------------------------------
extern "C" void kernel_launch(void* const* d_in, const int* in_sizes, int n_in,
                              void* d_out, int out_size, void* d_ws, size_t ws_size,
                              hipStream_t stream)
{
    const float* x      = (const float*)d_in[0];
    const float* qkv_w  = (const float*)d_in[1];
    const float* qkv_b  = (const float*)d_in[2];
    const float* qn_w   = (const float*)d_in[3];
    const float* kn_w   = (const float*)d_in[4];
    const float* proj_w = (const float*)d_in[5];
    const float* proj_b = (const float*)d_in[6];

    char* base = (char*)d_ws;
    unsigned short* pwb = (unsigned short*)(base + 256);// 2 MB
    unsigned short* qb  = pwb + 1048576;                // 8 MB
    unsigned short* kb  = qb  + 4194304;                // 8 MB
    unsigned short* vt  = kb  + 4194304;                // 8 MB
    unsigned short* ao  = vt  + 4194304;                // 8 MB
    unsigned short* xb  = ao  + 4194304;                // 8 MB  (dead after gemm_qkv)
    unsigned short* qwb = xb  + 4194304;                // 6 MB  (dead after gemm_qkv)
    unsigned short* po  = xb;                           // 16 MB (overlays xb+qwb+2MB)
    float* pl           = (float*)(po + 8388608);       // 512 KB

    prep<<<8192, 256, 0, stream>>>(x, qkv_w, proj_w, xb, qwb, pwb);

    gemm_qkv<<<dim3(24, 32), 256, 0, stream>>>(xb, qwb, qkv_b, qn_w, kn_w,
                                               qb, kb, vt);

    flash_mfma<<<dim3(32, 32, 2), 128, 0, stream>>>(qb, kb, vt, po, pl);

    combine<<<2048, 256, 0, stream>>>(po, pl, ao);

    gemm_out<<<dim3(8, 64), 256, 0, stream>>>(ao, pwb, proj_b, (float*)d_out);
}

// Round 9
// 205.256 us; speedup vs baseline: 1.0793x; 1.0388x over previous
//
#include <hip/hip_runtime.h>

typedef __attribute__((ext_vector_type(8))) short short8;
typedef __attribute__((ext_vector_type(4))) float f32x4;
typedef __attribute__((ext_vector_type(16))) float f32x16;

__device__ __forceinline__ float bf2f(unsigned short u) {
    union { unsigned int i; float f; } c; c.i = ((unsigned int)u) << 16; return c.f;
}
__device__ __forceinline__ unsigned short f2bf(float f) {   // RNE
    union { float f; unsigned int i; } c; c.f = f;
    unsigned int u = c.i;
    return (unsigned short)((u + 0x7fffu + ((u >> 16) & 1u)) >> 16);
}

// async global->LDS, 16B per lane. LDS dest = wave-uniform base + lane*16.
__device__ __forceinline__ void glds16(const void* g, void* l) {
    __builtin_amdgcn_global_load_lds(
        (const __attribute__((address_space(1))) unsigned int*)g,
        (__attribute__((address_space(3))) unsigned int*)l, 16, 0, 0);
}

union i4s8 { int4 i; short8 s; };

// SCL = (1/sqrt(64)) * log2(e), folded into q at gemm_qkv epilogue.
#define SCL_F 0.18033688011112042f

// ---------------------------------------------------------------------------
// prep: fp32->bf16 for x / qkv_w / proj_w.   (round-7 validated)
// ---------------------------------------------------------------------------
__global__ __launch_bounds__(256) void prep(
    const float* __restrict__ x, const float* __restrict__ qkv_w,
    const float* __restrict__ proj_w,
    unsigned short* __restrict__ xb, unsigned short* __restrict__ qwb,
    unsigned short* __restrict__ pwb)
{
    const int b = blockIdx.x, tid = threadIdx.x;
    const float* src; unsigned short* dst; int i;
    if (b < 4096)      { src = x;      dst = xb;  i = b * 256 + tid; }
    else if (b < 7168) { src = qkv_w;  dst = qwb; i = (b - 4096) * 256 + tid; }
    else               { src = proj_w; dst = pwb; i = (b - 7168) * 256 + tid; }
    float4 v = ((const float4*)src)[i];
    ushort4 o;
    o.x = f2bf(v.x); o.y = f2bf(v.y); o.z = f2bf(v.z); o.w = f2bf(v.w);
    ((ushort4*)dst)[i] = o;
}

// ---------------------------------------------------------------------------
// QKV GEMM (NT) + fused bias + RMSNorm + segmented RoPE epilogue.
// 128x128 tile, BK=64, 16x16x32 MFMA, 4 waves 2x2.   (round-7 validated)
// q additionally scaled by SCL_F. V-tile transposed through LDS -> vt[bh][d][n].
// ---------------------------------------------------------------------------
__global__ __launch_bounds__(256) void gemm_qkv(
    const unsigned short* __restrict__ A,
    const unsigned short* __restrict__ W,
    const float* __restrict__ bias,
    const float* __restrict__ qn_w, const float* __restrict__ kn_w,
    unsigned short* __restrict__ qb, unsigned short* __restrict__ kb,
    unsigned short* __restrict__ vt)
{
    __shared__ unsigned short pool[128 * 136];   // loop: As 16KB | Ws 16KB; epi: 34.8KB
    const int tid = threadIdx.x;
    const int w = tid >> 6, l = tid & 63, quad = l >> 4, low = l & 15;
    const int m0 = blockIdx.y * 128, n0 = blockIdx.x * 128;
    const int wm = w >> 1, wn = w & 1;
    const int K = 1024;

    f32x4 acc[4][4];
#pragma unroll
    for (int i = 0; i < 4; i++)
#pragma unroll
        for (int j = 0; j < 4; j++) acc[i][j] = (f32x4){0.f, 0.f, 0.f, 0.f};

    const int r1 = tid >> 3, p1 = tid & 7, c1 = p1 ^ (r1 & 7);
    const unsigned short* ga = A + (size_t)(m0 + r1) * K + c1 * 8;
    const unsigned short* gw = W + (size_t)(n0 + r1) * K + c1 * 8;
    char* lA = (char*)pool + (w << 10);
    char* lW = (char*)pool + 16384 + (w << 10);

    for (int k0 = 0; k0 < K; k0 += 64) {
        __syncthreads();
        glds16(ga + k0,            lA);
        glds16(ga + k0 + 32 * K,   lA + 4096);
        glds16(ga + k0 + 64 * K,   lA + 8192);
        glds16(ga + k0 + 96 * K,   lA + 12288);
        glds16(gw + k0,            lW);
        glds16(gw + k0 + 32 * K,   lW + 4096);
        glds16(gw + k0 + 64 * K,   lW + 8192);
        glds16(gw + k0 + 96 * K,   lW + 12288);
        __syncthreads();
#pragma unroll
        for (int ks = 0; ks < 2; ks++) {
            short8 af[4], wf[4];
#pragma unroll
            for (int i = 0; i < 4; i++) {
                const int ra = wm * 64 + i * 16 + low;
                af[i] = *(const short8*)&pool[ra * 64 + ((ks * 4 + quad) ^ (ra & 7)) * 8];
                const int rw = wn * 64 + i * 16 + low;
                wf[i] = *(const short8*)&pool[8192 + rw * 64 + ((ks * 4 + quad) ^ (rw & 7)) * 8];
            }
#pragma unroll
            for (int i = 0; i < 4; i++)
#pragma unroll
                for (int j = 0; j < 4; j++)
                    acc[i][j] = __builtin_amdgcn_mfma_f32_16x16x32_bf16(
                        af[i], wf[j], acc[i][j], 0, 0, 0);
        }
    }

    const int colbase = n0 + wn * 64;
    const int t3 = n0 >> 10;
    const int hh = (colbase & 1023) >> 6;

    if (t3 == 2) {
        __syncthreads();
#pragma unroll
        for (int i = 0; i < 4; i++)
#pragma unroll
            for (int j = 0; j < 4; j++) {
                const int c = wn * 64 + j * 16 + low;
                const float bv = bias[n0 + c];
#pragma unroll
                for (int reg = 0; reg < 4; reg++) {
                    const int r = wm * 64 + i * 16 + quad * 4 + reg;
                    pool[c * 136 + r] = f2bf(acc[i][j][reg] + bv);
                }
            }
        __syncthreads();
        const int b_ = m0 >> 11, nbase = m0 & 2047;
        const int rch = (tid & 15) * 8;
#pragma unroll
        for (int p = 0; p < 8; p++) {
            const int c = (tid >> 4) + p * 16;
            const int gc = n0 + c;
            const int h2 = (gc & 1023) >> 6, d = gc & 63;
            const short8 vv = *(const short8*)&pool[c * 136 + rch];
            *(short8*)(vt + ((size_t)((b_ * 16 + h2) * 64 + d)) * 2048 + nbase + rch) = vv;
        }
        return;
    }

    const float* nw = (t3 == 0) ? qn_w : kn_w;
    const float wscl = (t3 == 0) ? SCL_F : 1.0f;   // fold softmax scale into q
    float wv4[4];
#pragma unroll
    for (int j = 0; j < 4; j++) wv4[j] = nw[j * 16 + low] * wscl;
    const float c0 = -2.0f * 13.287712379549449f / 64.0f;   // -2*log2(1e4)/64
    const float invA = exp2f(c0 * (float)low);
    const float invB = exp2f(c0 * (float)(16 + low));
    unsigned short* dqk = (t3 == 0) ? qb : kb;

#pragma unroll
    for (int i = 0; i < 4; i++) {
#pragma unroll
        for (int reg = 0; reg < 4; reg++) {
            const int gm = m0 + wm * 64 + i * 16 + quad * 4 + reg;
            const int b_ = gm >> 11, npos = gm & 2047;
            float v[4];
#pragma unroll
            for (int j = 0; j < 4; j++)
                v[j] = acc[i][j][reg] + bias[colbase + j * 16 + low];
            float ss = v[0]*v[0] + v[1]*v[1] + v[2]*v[2] + v[3]*v[3];
            ss += __shfl_xor(ss, 1); ss += __shfl_xor(ss, 2);
            ss += __shfl_xor(ss, 4); ss += __shfl_xor(ss, 8);
            const float r = rsqrtf(ss * (1.0f / 64.0f) + 1e-6f);
            float nv[4];
#pragma unroll
            for (int j = 0; j < 4; j++) nv[j] = v[j] * r * wv4[j];
            float o0, o1, o2, o3;
            if (npos < 1536) {
                const float p = (float)((npos < 1024) ? npos : (npos - 1024));
                float sA, cA, sB, cB;
                __sincosf(p * invA, &sA, &cA);
                __sincosf(p * invB, &sB, &cB);
                o0 = nv[0] * cA - nv[2] * sA;
                o1 = nv[1] * cB - nv[3] * sB;
                o2 = nv[2] * cA + nv[0] * sA;
                o3 = nv[3] * cB + nv[1] * sB;
            } else { o0 = nv[0]; o1 = nv[1]; o2 = nv[2]; o3 = nv[3]; }
            unsigned short* drow =
                dqk + ((size_t)(b_ * 16 + hh) * 2048 + npos) * 64 + low;
            drow[0]  = f2bf(o0);
            drow[16] = f2bf(o1);
            drow[32] = f2bf(o2);
            drow[48] = f2bf(o3);
        }
    }
}

// ---------------------------------------------------------------------------
// MFMA flash attention (round-6 validated config), 32x32x16, scale pre-folded
// into q (round-7 validated exponent path: exp2f(s), no offset).
// Grid (16 qtiles, 32 bh, 2 halves); block = 128 q-rows, 4 waves x 32.
// 8 tiles of 128 keys (K 16KB + V^T 16KB LDS). Partials -> po/pl.
// ---------------------------------------------------------------------------
__global__ __launch_bounds__(256, 4) void flash_mfma(
    const unsigned short* __restrict__ qg, const unsigned short* __restrict__ kg,
    const unsigned short* __restrict__ vg, unsigned short* __restrict__ po,
    float* __restrict__ pl)
{
    __shared__ unsigned short Ks[128 * 64];   // [key][d]   rows 128B, 8 chunks
    __shared__ unsigned short Vs[64 * 128];   // [d][key]   rows 256B, 16 chunks

    const int tid = threadIdx.x;
    const int w = tid >> 6, lane = tid & 63, h5 = lane >> 5, l5 = lane & 31;
    const int bh = blockIdx.y, q0 = blockIdx.x * 128, half = blockIdx.z;

    short8 qf[4];
    {
        const unsigned short* qrow = qg + ((size_t)bh * 2048 + q0 + w * 32 + l5) * 64;
#pragma unroll
        for (int ks = 0; ks < 4; ks++)
            qf[ks] = *(const short8*)(qrow + ks * 16 + h5 * 8);
    }

    f32x16 o0, o1, ls;
#pragma unroll
    for (int i = 0; i < 16; i++) { o0[i] = 0.f; o1[i] = 0.f; ls[i] = 0.f; }
    i4s8 ones; ones.i = make_int4(0x3F803F80, 0x3F803F80, 0x3F803F80, 0x3F803F80);

    const int krr = tid >> 3, kc = (tid & 7) ^ (krr & 7);
    const unsigned short* gk = kg + ((size_t)bh * 2048 + krr) * 64 + kc * 8;
    const int vrr = tid >> 4, vc = (tid & 15) ^ (vrr & 15);
    const unsigned short* gv = vg + ((size_t)bh * 64 + vrr) * 2048 + vc * 8;
    char* lK = (char*)Ks + (w << 10);
    char* lV = (char*)Vs + (w << 10);
    const int kbase = half * 1024;

    for (int kt = 0; kt < 8; kt++) {
        const size_t ko = (size_t)(kbase + kt * 128);
        __syncthreads();
        glds16(gk + ko * 64,         lK);
        glds16(gk + ko * 64 + 2048,  lK + 4096);
        glds16(gk + ko * 64 + 4096,  lK + 8192);
        glds16(gk + ko * 64 + 6144,  lK + 12288);
        glds16(gv + ko,              lV);
        glds16(gv + ko + 32768,      lV + 4096);
        glds16(gv + ko + 65536,      lV + 8192);
        glds16(gv + ko + 98304,      lV + 12288);
        __syncthreads();

#pragma unroll
        for (int kbk = 0; kbk < 4; kbk++) {
            f32x16 s;
#pragma unroll
            for (int i = 0; i < 16; i++) s[i] = 0.f;
            const int krow = kbk * 32 + l5;
#pragma unroll
            for (int ks = 0; ks < 4; ks++) {
                const int ch = (h5 + 2 * ks) ^ (krow & 7);
                const short8 kf = *(const short8*)&Ks[krow * 64 + ch * 8];
                s = __builtin_amdgcn_mfma_f32_32x32x16_bf16(kf, qf[ks], s, 0, 0, 0);
            }
            unsigned int dw[8], pdw[8];
#pragma unroll
            for (int r = 0; r < 8; r++) {
                union { float f; unsigned int u; } a, b;
                a.f = exp2f(s[2 * r]);
                b.f = exp2f(s[2 * r + 1]);
                dw[r] = __builtin_amdgcn_perm(b.u, a.u, 0x07060302u);
            }
#pragma unroll
            for (int r = 0; r < 8; r++) pdw[r] = __shfl_xor((int)dw[r], 32);
            i4s8 f0, f1;
            f0.i.x = h5 ? pdw[2] : dw[0];
            f0.i.y = h5 ? pdw[3] : dw[1];
            f0.i.z = h5 ? dw[2]  : pdw[0];
            f0.i.w = h5 ? dw[3]  : pdw[1];
            f1.i.x = h5 ? pdw[6] : dw[4];
            f1.i.y = h5 ? pdw[7] : dw[5];
            f1.i.z = h5 ? dw[6]  : pdw[4];
            f1.i.w = h5 ? dw[7]  : pdw[5];

            ls = __builtin_amdgcn_mfma_f32_32x32x16_bf16(f0.s, ones.s, ls, 0, 0, 0);
            ls = __builtin_amdgcn_mfma_f32_32x32x16_bf16(f1.s, ones.s, ls, 0, 0, 0);

#pragma unroll
            for (int nb = 0; nb < 2; nb++) {
                const int vrow = nb * 32 + l5;
                const int chb = kbk * 4 + h5;
                const short8 vfa = *(const short8*)&Vs[vrow * 128 + ((chb    ) ^ (vrow & 15)) * 8];
                const short8 vfb = *(const short8*)&Vs[vrow * 128 + ((chb + 2) ^ (vrow & 15)) * 8];
                f32x16& oo = nb ? o1 : o0;
                oo = __builtin_amdgcn_mfma_f32_32x32x16_bf16(f0.s, vfa, oo, 0, 0, 0);
                oo = __builtin_amdgcn_mfma_f32_32x32x16_bf16(f1.s, vfb, oo, 0, 0, 0);
            }
        }
    }

    unsigned short* pob = po + ((size_t)(half * 32 + bh)) * 2048 * 64;
    float* plb = pl + ((size_t)(half * 32 + bh)) * 2048;
#pragma unroll
    for (int r = 0; r < 16; r++) {
        const int qrow = q0 + w * 32 + (r & 3) + 8 * (r >> 2) + 4 * h5;
        pob[(size_t)qrow * 64 + l5]      = f2bf(o0[r]);
        pob[(size_t)qrow * 64 + 32 + l5] = f2bf(o1[r]);
        if (l5 == 0) plb[qrow] = ls[r];
    }
}

// ---------------------------------------------------------------------------
// combine: ao[b][n][h*64+d] = (po0+po1) / (pl0+pl1).   (validated)
// ---------------------------------------------------------------------------
__global__ __launch_bounds__(256) void combine(
    const unsigned short* __restrict__ po, const float* __restrict__ pl,
    unsigned short* __restrict__ ao)
{
    const int g = blockIdx.x * 256 + threadIdx.x;
    const int row = g >> 3;
    const int c8 = (g & 7) * 8;
    const int bh = row >> 11, n = row & 2047;
    const float inv = 1.0f / (pl[row] + pl[65536 + row]);
    const short8 a = *(const short8*)(po + (size_t)row * 64 + c8);
    const short8 b = *(const short8*)(po + 4194304 + (size_t)row * 64 + c8);
    short8 r;
#pragma unroll
    for (int j = 0; j < 8; j++)
        r[j] = (short)f2bf((bf2f((unsigned short)a[j]) + bf2f((unsigned short)b[j])) * inv);
    const int b_ = bh >> 4, h = bh & 15;
    *(short8*)(ao + ((size_t)(b_ * 2048 + n)) * 1024 + h * 64 + c8) = r;
}

// ---------------------------------------------------------------------------
// Output projection: 64x128 tile, BK=64, 16x16x32 MFMA, grid (8,64), fp32 out.
// (round-7 validated)
// ---------------------------------------------------------------------------
__global__ __launch_bounds__(256) void gemm_out(
    const unsigned short* __restrict__ A,
    const unsigned short* __restrict__ W,
    const float* __restrict__ bias,
    float* __restrict__ outp)
{
    __shared__ unsigned short As[64 * 64];    // 8 KB
    __shared__ unsigned short Ws[128 * 64];   // 16 KB
    const int tid = threadIdx.x;
    const int w = tid >> 6, l = tid & 63, quad = l >> 4, low = l & 15;
    const int m0 = blockIdx.y * 64, n0 = blockIdx.x * 128;
    const int wm = w >> 1, wn = w & 1;
    const int K = 1024;

    f32x4 acc[2][4];
#pragma unroll
    for (int i = 0; i < 2; i++)
#pragma unroll
        for (int j = 0; j < 4; j++) acc[i][j] = (f32x4){0.f, 0.f, 0.f, 0.f};

    const int r1 = tid >> 3, p1 = tid & 7, c1 = p1 ^ (r1 & 7);
    const unsigned short* ga = A + (size_t)(m0 + r1) * K + c1 * 8;
    const unsigned short* gw = W + (size_t)(n0 + r1) * K + c1 * 8;
    char* lA = (char*)As + (w << 10);
    char* lW = (char*)Ws + (w << 10);

    for (int k0 = 0; k0 < K; k0 += 64) {
        __syncthreads();
        glds16(ga + k0,           lA);
        glds16(ga + k0 + 32 * K,  lA + 4096);
        glds16(gw + k0,           lW);
        glds16(gw + k0 + 32 * K,  lW + 4096);
        glds16(gw + k0 + 64 * K,  lW + 8192);
        glds16(gw + k0 + 96 * K,  lW + 12288);
        __syncthreads();
#pragma unroll
        for (int ks = 0; ks < 2; ks++) {
            short8 af[2], wf[4];
#pragma unroll
            for (int i = 0; i < 2; i++) {
                const int ra = wm * 32 + i * 16 + low;
                af[i] = *(const short8*)&As[ra * 64 + ((ks * 4 + quad) ^ (ra & 7)) * 8];
            }
#pragma unroll
            for (int j = 0; j < 4; j++) {
                const int rw = wn * 64 + j * 16 + low;
                wf[j] = *(const short8*)&Ws[rw * 64 + ((ks * 4 + quad) ^ (rw & 7)) * 8];
            }
#pragma unroll
            for (int i = 0; i < 2; i++)
#pragma unroll
                for (int j = 0; j < 4; j++)
                    acc[i][j] = __builtin_amdgcn_mfma_f32_16x16x32_bf16(
                        af[i], wf[j], acc[i][j], 0, 0, 0);
        }
    }

#pragma unroll
    for (int i = 0; i < 2; i++)
#pragma unroll
        for (int j = 0; j < 4; j++) {
            const int gc = n0 + wn * 64 + j * 16 + low;
            const float bv = bias[gc];
#pragma unroll
            for (int reg = 0; reg < 4; reg++) {
                const int gm = m0 + wm * 32 + i * 16 + quad * 4 + reg;
                outp[(size_t)gm * 1024 + gc] = acc[i][j][reg] + bv;
            }
        }
}

// ---------------------------------------------------------------------------
extern "C" void kernel_launch(void* const* d_in, const int* in_sizes, int n_in,
                              void* d_out, int out_size, void* d_ws, size_t ws_size,
                              hipStream_t stream)
{
    const float* x      = (const float*)d_in[0];
    const float* qkv_w  = (const float*)d_in[1];
    const float* qkv_b  = (const float*)d_in[2];
    const float* qn_w   = (const float*)d_in[3];
    const float* kn_w   = (const float*)d_in[4];
    const float* proj_w = (const float*)d_in[5];
    const float* proj_b = (const float*)d_in[6];

    char* base = (char*)d_ws;
    unsigned short* pwb = (unsigned short*)(base + 256);// 2 MB
    unsigned short* qb  = pwb + 1048576;                // 8 MB
    unsigned short* kb  = qb  + 4194304;                // 8 MB
    unsigned short* vt  = kb  + 4194304;                // 8 MB
    unsigned short* ao  = vt  + 4194304;                // 8 MB
    unsigned short* xb  = ao  + 4194304;                // 8 MB  (dead after gemm_qkv)
    unsigned short* qwb = xb  + 4194304;                // 6 MB  (dead after gemm_qkv)
    unsigned short* po  = xb;                           // 16 MB (overlays xb+qwb+2MB)
    float* pl           = (float*)(po + 8388608);       // 512 KB

    prep<<<8192, 256, 0, stream>>>(x, qkv_w, proj_w, xb, qwb, pwb);

    gemm_qkv<<<dim3(24, 32), 256, 0, stream>>>(xb, qwb, qkv_b, qn_w, kn_w,
                                               qb, kb, vt);

    flash_mfma<<<dim3(16, 32, 2), 256, 0, stream>>>(qb, kb, vt, po, pl);

    combine<<<2048, 256, 0, stream>>>(po, pl, ao);

    gemm_out<<<dim3(8, 64), 256, 0, stream>>>(ao, pwb, proj_b, (float*)d_out);
}